// Round 2
// 1039.986 us; speedup vs baseline: 1.1036x; 1.1036x over previous
//
#include <hip/hip_runtime.h>

typedef float v2f __attribute__((ext_vector_type(2)));
typedef float v4f __attribute__((ext_vector_type(4)));

#define HH 30
#define DIN 4

__device__ __forceinline__ float sigf(float v) {
    return __builtin_amdgcn_rcpf(1.0f + __expf(-v));
}
__device__ __forceinline__ v2f fma2(v2f a, v2f b, v2f c) {
    return __builtin_elementwise_fma(a, b, c);
}
__device__ __forceinline__ v2f splat2(float s) { return (v2f)s; }

// DPP reduce step: x += dpp_shifted(x), OOB/masked lanes contribute 0
template <int Ctrl, int RowMask>
__device__ __forceinline__ float dpp_step(float x) {
    union { float f; int i; } in, out;
    in.f = x;
    out.i = __builtin_amdgcn_update_dpp(0, in.i, Ctrl, RowMask, 0xf, false);
    return x + out.f;
}
// Sum across each 32-lane half; lane31 = sum(lanes 0..31), lane63 = sum(32..63).
__device__ __forceinline__ float half_reduce(float x) {
    x = dpp_step<0x111, 0xf>(x);   // row_shr:1
    x = dpp_step<0x112, 0xf>(x);   // row_shr:2
    x = dpp_step<0x114, 0xf>(x);   // row_shr:4
    x = dpp_step<0x118, 0xf>(x);   // row_shr:8
    x = dpp_step<0x142, 0xa>(x);   // row_bcast:15 into rows 1,3
    return x;
}

// Broadcast each 32-lane half's value to all 64 lanes.
// lo[l] = x[l & 31] (low half's value), hi[l] = x[32 + (l & 31)].
// gfx950 v_permlane32_swap_b32 with both srcs = x gives BOTH outputs in one
// VALU instruction — no DS pipe, no cndmask. Returns ext-vector uint2.
__device__ __forceinline__ void bcast_halves(int ahalf, float x, float& lo, float& hi) {
#if __has_builtin(__builtin_amdgcn_permlane32_swap)
    union { float f; unsigned u; } c; c.f = x;
    auto r = __builtin_amdgcn_permlane32_swap(c.u, c.u, false, false);
    union { unsigned u; float f; } o0, o1;
    o0.u = r[0];   // lanes 0..31 of dst kept, lanes 32..63 <- src lanes 0..31  => {x_lo, x_lo}
    o1.u = r[1];   // lanes 0..31 <- dst lanes 32..63, lanes 32..63 kept        => {x_hi, x_hi}
    lo = o0.f;
    hi = o1.f;
#else
    const float p = __shfl_xor(x, 32, 64);
    lo = ahalf ? p : x;
    hi = ahalf ? x : p;
#endif
}

// One wave per block, one batch element per wave.
// a = lane>>5: a=0 owns (i,f) gate rows, a=1 owns (g,o) rows; h = lane&31.
// Each lane holds 2 gate rows of each matrix packed float2 -> v_pk_fma_f32.
//
// ROTATED LOOP: iteration t computes L2(t) AND L1(t+1) concurrently.
// Both consume the same s1v (= h1(t)) read, so the three matrix products
// (Wih2@h1, Whh2@h2, Whh1@h1 + Wih1@x(t+1)) form 6 independent FMA chains,
// and the two activation/c-update tails are independent. Loop-carried
// critical path ~= max(L1,L2) instead of L1+L2 in series.
// Cross-half gate exchange via permlane32_swap (VALU) — no DS on the path.
__global__ __attribute__((amdgpu_flat_work_group_size(64, 64),
                          amdgpu_waves_per_eu(2, 2)))
void lstm2_kernel(const float* __restrict__ x,
                  const float* __restrict__ Wih1, const float* __restrict__ bih1,
                  const float* __restrict__ Whh1, const float* __restrict__ bhh1,
                  const float* __restrict__ Wih2, const float* __restrict__ bih2,
                  const float* __restrict__ Whh2, const float* __restrict__ bhh2,
                  const float* __restrict__ Wlin, const float* __restrict__ blin,
                  float* __restrict__ out, int T)
{
    const int tid = threadIdx.x;
    const int a = tid >> 5;
    const int h = tid & 31;
    const bool act = (h < HH);
    const int hc = act ? h : (HH - 1);
    const int r0 = (2 * a) * HH + hc;
    const int r1 = (2 * a + 1) * HH + hc;
    const int b = blockIdx.x;

    __shared__ __align__(16) float sh1[32];
    __shared__ __align__(16) float sh2[32];

    // ---- per-lane packed weights ----
    v2f wx[DIN], wh1[HH], wi2[HH], wh2[HH];
#pragma unroll
    for (int c = 0; c < DIN; ++c)
        wx[c] = (v2f){Wih1[r0 * DIN + c], Wih1[r1 * DIN + c]};
#pragma unroll
    for (int k = 0; k < HH; ++k) {
        wh1[k] = (v2f){Whh1[r0 * HH + k], Whh1[r1 * HH + k]};
        wi2[k] = (v2f){Wih2[r0 * HH + k], Wih2[r1 * HH + k]};
        wh2[k] = (v2f){Whh2[r0 * HH + k], Whh2[r1 * HH + k]};
    }
    const v2f bias1 = (v2f){bih1[r0] + bhh1[r0], bih1[r1] + bhh1[r1]};
    const v2f bias2 = (v2f){bih2[r0] + bhh2[r0], bih2[r1] + bhh2[r1]};
    const v2f wlo = act ? (v2f){Wlin[(2 * a) * HH + hc], Wlin[(2 * a + 1) * HH + hc]}
                        : splat2(0.0f);
    const v2f blv = (v2f){blin[2 * a], blin[2 * a + 1]};

    // act0 = sigmoid (a=0: i-gate) or tanh = 2*sig(2v)-1 (a=1: g-gate)
    const float inS  = a ? 2.0f : 1.0f;
    const float outS = a ? 2.0f : 1.0f;
    const float outB = a ? -1.0f : 0.0f;

    float c1 = 0.0f, c2 = 0.0f;
    sh1[h] = 0.0f;
    sh2[h] = 0.0f;

    const v4f* xp = reinterpret_cast<const v4f*>(x) + (size_t)b * T;
    v2f* op = reinterpret_cast<v2f*>(out) + (size_t)b * T * 2 + a;
    const v4f* s1v = reinterpret_cast<const v4f*>(sh1);
    const v4f* s2v = reinterpret_cast<const v4f*>(sh2);

    // ---- prologue: L1(0) with h1_{-1} = 0 (no Whh1 terms) ----
    {
        const v4f x0 = xp[0];
        v2f P = bias1;
        P = fma2(wx[0], splat2(x0.x), P);
        P = fma2(wx[1], splat2(x0.y), P);
        P = fma2(wx[2], splat2(x0.z), P);
        P = fma2(wx[3], splat2(x0.w), P);
        float a0v = fmaf(outS, sigf(inS * P.x), outB);   // i (a=0) / g (a=1)
        float a1v = sigf(P.y);                           // f (a=0) / o (a=1)
        float iv, gv, fv, ov;
        bcast_halves(a, a0v, iv, gv);
        bcast_halves(a, a1v, fv, ov);
        (void)fv;                                        // c1 starts at 0
        c1 = iv * gv;
        const float h1n = ov * fmaf(2.0f, sigf(2.0f * c1), -1.0f);
        sh1[h] = h1n;                                    // h1(0)
    }
    v4f xc = xp[(T > 1) ? 1 : 0];                        // x(1)

    // Loop invariant at iteration t: sh1 = h1(t), sh2 = h2(t-1),
    // c1 = c1(t), c2 = c2(t-1), xc = x(t+1).
    for (int t = 0; t < T; ++t) {
        const v4f xn = xp[(t + 2 < T) ? (t + 2) : (T - 1)];  // prefetch x(t+2)

        // ===== 6 independent FMA chains =====
        // Ba/Bb : Wih2 @ h1(t) + bias2       (L2 input path)
        // Bc/Bd : Whh2 @ h2(t-1)             (L2 recurrent path)
        // A0/A1 : Whh1 @ h1(t) + Wih1 @ x(t+1) + bias1   (L1 for step t+1)
        v2f Ba = bias2, Bb = splat2(0.0f);
        v2f A0 = bias1, A1 = splat2(0.0f);
        v2f Bc = splat2(0.0f), Bd = splat2(0.0f);

        A0 = fma2(wx[0], splat2(xc.x), A0);
        A0 = fma2(wx[1], splat2(xc.y), A0);
        A0 = fma2(wx[2], splat2(xc.z), A0);
        A0 = fma2(wx[3], splat2(xc.w), A0);

#pragma unroll
        for (int j = 0; j < 7; ++j) {
            const v4f u = s1v[j];            // h1(t), read ONCE, feeds 2 chains
            const v4f v = s2v[j];            // h2(t-1)
            if (j & 1) {
                Bb = fma2(wi2[4 * j + 0], splat2(u.x), Bb);
                Bb = fma2(wi2[4 * j + 1], splat2(u.y), Bb);
                Bb = fma2(wi2[4 * j + 2], splat2(u.z), Bb);
                Bb = fma2(wi2[4 * j + 3], splat2(u.w), Bb);
                A1 = fma2(wh1[4 * j + 0], splat2(u.x), A1);
                A1 = fma2(wh1[4 * j + 1], splat2(u.y), A1);
                A1 = fma2(wh1[4 * j + 2], splat2(u.z), A1);
                A1 = fma2(wh1[4 * j + 3], splat2(u.w), A1);
                Bd = fma2(wh2[4 * j + 0], splat2(v.x), Bd);
                Bd = fma2(wh2[4 * j + 1], splat2(v.y), Bd);
                Bd = fma2(wh2[4 * j + 2], splat2(v.z), Bd);
                Bd = fma2(wh2[4 * j + 3], splat2(v.w), Bd);
            } else {
                Ba = fma2(wi2[4 * j + 0], splat2(u.x), Ba);
                Ba = fma2(wi2[4 * j + 1], splat2(u.y), Ba);
                Ba = fma2(wi2[4 * j + 2], splat2(u.z), Ba);
                Ba = fma2(wi2[4 * j + 3], splat2(u.w), Ba);
                A0 = fma2(wh1[4 * j + 0], splat2(u.x), A0);
                A0 = fma2(wh1[4 * j + 1], splat2(u.y), A0);
                A0 = fma2(wh1[4 * j + 2], splat2(u.z), A0);
                A0 = fma2(wh1[4 * j + 3], splat2(u.w), A0);
                Bc = fma2(wh2[4 * j + 0], splat2(v.x), Bc);
                Bc = fma2(wh2[4 * j + 1], splat2(v.y), Bc);
                Bc = fma2(wh2[4 * j + 2], splat2(v.z), Bc);
                Bc = fma2(wh2[4 * j + 3], splat2(v.w), Bc);
            }
        }
        {
            const v4f u = s1v[7];            // only elements 28,29 are live
            const v4f v = s2v[7];
            Bb = fma2(wi2[28], splat2(u.x), Bb);
            Bb = fma2(wi2[29], splat2(u.y), Bb);
            A1 = fma2(wh1[28], splat2(u.x), A1);
            A1 = fma2(wh1[29], splat2(u.y), A1);
            Bd = fma2(wh2[28], splat2(v.x), Bd);
            Bd = fma2(wh2[29], splat2(v.y), Bd);
        }

        // ===== two independent activation/update tails, interleaved =====
        const v2f Bv = (Ba + Bb) + (Bc + Bd);
        const v2f Av = A0 + A1;

        float b0 = fmaf(outS, sigf(inS * Bv.x), outB);   // L2: i/g
        float b1 = sigf(Bv.y);                           // L2: f/o
        float a0v = fmaf(outS, sigf(inS * Av.x), outB);  // L1(t+1): i/g
        float a1v = sigf(Av.y);                          // L1(t+1): f/o

        float iv2, gv2, fv2, ov2, iv1, gv1, fv1, ov1;
        bcast_halves(a, b0, iv2, gv2);
        bcast_halves(a, b1, fv2, ov2);
        bcast_halves(a, a0v, iv1, gv1);
        bcast_halves(a, a1v, fv1, ov1);

        c2 = fmaf(fv2, c2, iv2 * gv2);
        c1 = fmaf(fv1, c1, iv1 * gv1);
        const float h2n = ov2 * fmaf(2.0f, sigf(2.0f * c2), -1.0f);  // h2(t)
        const float h1n = ov1 * fmaf(2.0f, sigf(2.0f * c1), -1.0f);  // h1(t+1)
        sh2[h] = h2n;
        sh1[h] = h1n;

        // ===== head: out(t) = Wlin @ h2(t) + b — VALU-pipe DPP reduce =====
        const v2f pv = wlo * splat2(h2n);                // 0 on pad lanes
        const float rx = half_reduce(pv.x);
        const float ry = half_reduce(pv.y);
        if ((tid & 31) == 31) {                          // lane31 (a=0), lane63 (a=1)
            op[2 * t] = (v2f){rx + blv.x, ry + blv.y};
        }
        xc = xn;
    }
}

extern "C" void kernel_launch(void* const* d_in, const int* in_sizes, int n_in,
                              void* d_out, int out_size, void* d_ws, size_t ws_size,
                              hipStream_t stream)
{
    const float* x    = (const float*)d_in[0];
    const float* Wih1 = (const float*)d_in[1];
    const float* bih1 = (const float*)d_in[2];
    const float* Whh1 = (const float*)d_in[3];
    const float* bhh1 = (const float*)d_in[4];
    const float* Wih2 = (const float*)d_in[5];
    const float* bih2 = (const float*)d_in[6];
    const float* Whh2 = (const float*)d_in[7];
    const float* bhh2 = (const float*)d_in[8];
    const float* Wlin = (const float*)d_in[9];
    const float* blin = (const float*)d_in[10];
    float* out = (float*)d_out;

    const int T = 1024;
    const int B = in_sizes[0] / (T * DIN);   // 2048

    hipLaunchKernelGGL(lstm2_kernel, dim3(B), dim3(64), 0, stream,
                       x, Wih1, bih1, Whh1, bhh1, Wih2, bih2, Whh2, bhh2,
                       Wlin, blin, out, T);
}

// Round 3
// 1021.276 us; speedup vs baseline: 1.1238x; 1.0183x over previous
//
#include <hip/hip_runtime.h>

typedef float v2f __attribute__((ext_vector_type(2)));
typedef float v4f __attribute__((ext_vector_type(4)));

#define HH 30
#define DIN 4

#if __has_builtin(__builtin_amdgcn_exp2f)
#define EXP2F(v) __builtin_amdgcn_exp2f(v)
#else
#define EXP2F(v) exp2f(v)
#endif

// Pre-scaled sigmoid: caller folded -log2(e) (or -2*log2(e) for tanh-as-sig)
// into the weights/bias, so sigmoid(raw) == rcp(1 + exp2(v)) directly.
__device__ __forceinline__ float sig2f(float v) {
    return __builtin_amdgcn_rcpf(1.0f + EXP2F(v));
}
__device__ __forceinline__ v2f fma2(v2f a, v2f b, v2f c) {
    return __builtin_elementwise_fma(a, b, c);
}
__device__ __forceinline__ v2f splat2(float s) { return (v2f)s; }

// DPP reduce step: x += dpp_shifted(x), OOB/masked lanes contribute 0
template <int Ctrl, int RowMask>
__device__ __forceinline__ float dpp_step(float x) {
    union { float f; int i; } in, out;
    in.f = x;
    out.i = __builtin_amdgcn_update_dpp(0, in.i, Ctrl, RowMask, 0xf, false);
    return x + out.f;
}
// Sum across each 32-lane half; lane31 = sum(lanes 0..31), lane63 = sum(32..63).
__device__ __forceinline__ float half_reduce(float x) {
    x = dpp_step<0x111, 0xf>(x);   // row_shr:1
    x = dpp_step<0x112, 0xf>(x);   // row_shr:2
    x = dpp_step<0x114, 0xf>(x);   // row_shr:4
    x = dpp_step<0x118, 0xf>(x);   // row_shr:8
    x = dpp_step<0x142, 0xa>(x);   // row_bcast:15 into rows 1,3
    return x;
}

// Broadcast each 32-lane half's value to all 64 lanes via permlane32_swap
// (single VALU instr, both outputs; no DS pipe).
__device__ __forceinline__ void bcast_halves(int ahalf, float x, float& lo, float& hi) {
#if __has_builtin(__builtin_amdgcn_permlane32_swap)
    union { float f; unsigned u; } c; c.f = x;
    auto r = __builtin_amdgcn_permlane32_swap(c.u, c.u, false, false);
    union { unsigned u; float f; } o0, o1;
    o0.u = r[0];   // {x_lo, x_lo}
    o1.u = r[1];   // {x_hi, x_hi}
    lo = o0.f;
    hi = o1.f;
#else
    const float p = __shfl_xor(x, 32, 64);
    lo = ahalf ? p : x;
    hi = ahalf ? x : p;
#endif
}

// One wave per block, one batch element per wave.
// a = lane>>5: a=0 owns (i,f) gate rows, a=1 owns (g,o) rows; h = lane&31.
// Each lane holds 2 gate rows of each matrix packed float2 -> v_pk_fma_f32.
//
// ROTATED LOOP: iteration t computes L2(t) AND L1(t+1) concurrently (6
// independent FMA chains + 2 independent activation tails).
//
// NEW this round:
//  * phase-stagger: co-resident waves on a SIMD run identical code and
//    plausibly stall in lockstep (VALUBusy 68%, 32% dual-stall). A one-time
//    s_sleep prologue keyed on blockIdx&3 offsets wave phases so one wave's
//    matrix phase covers its neighbor's serial activation tail.
//  * exp2 weight folding: gate rows pre-scaled by -log2e (g rows by
//    -2*log2e) so sigmoid = rcp(1+exp2(v)) with no per-activation mul.
__global__ __attribute__((amdgpu_flat_work_group_size(64, 64),
                          amdgpu_waves_per_eu(2, 2)))
void lstm2_kernel(const float* __restrict__ x,
                  const float* __restrict__ Wih1, const float* __restrict__ bih1,
                  const float* __restrict__ Whh1, const float* __restrict__ bhh1,
                  const float* __restrict__ Wih2, const float* __restrict__ bih2,
                  const float* __restrict__ Whh2, const float* __restrict__ bhh2,
                  const float* __restrict__ Wlin, const float* __restrict__ blin,
                  float* __restrict__ out, int T)
{
    const int tid = threadIdx.x;
    const int a = tid >> 5;
    const int h = tid & 31;
    const bool act = (h < HH);
    const int hc = act ? h : (HH - 1);
    const int r0 = (2 * a) * HH + hc;
    const int r1 = (2 * a + 1) * HH + hc;
    const int b = blockIdx.x;

    __shared__ __align__(16) float sh1[32];
    __shared__ __align__(16) float sh2[32];

    // Row scale: i/f/o rows -log2e; g rows (r0 of half a=1) -2*log2e.
    const float L2E = 1.44269504088896340736f;
    const v2f sc = a ? (v2f){-2.0f * L2E, -L2E} : (v2f){-L2E, -L2E};
    const float M2 = -2.0f * L2E;          // tanh(c) = 2*rcp(1+exp2(M2*c))-1

    // ---- per-lane packed weights (pre-scaled) ----
    v2f wx[DIN], wh1[HH], wi2[HH], wh2[HH];
#pragma unroll
    for (int c = 0; c < DIN; ++c)
        wx[c] = (v2f){Wih1[r0 * DIN + c], Wih1[r1 * DIN + c]} * sc;
#pragma unroll
    for (int k = 0; k < HH; ++k) {
        wh1[k] = (v2f){Whh1[r0 * HH + k], Whh1[r1 * HH + k]} * sc;
        wi2[k] = (v2f){Wih2[r0 * HH + k], Wih2[r1 * HH + k]} * sc;
        wh2[k] = (v2f){Whh2[r0 * HH + k], Whh2[r1 * HH + k]} * sc;
    }
    const v2f bias1 = (v2f){bih1[r0] + bhh1[r0], bih1[r1] + bhh1[r1]} * sc;
    const v2f bias2 = (v2f){bih2[r0] + bhh2[r0], bih2[r1] + bhh2[r1]} * sc;
    const v2f wlo = act ? (v2f){Wlin[(2 * a) * HH + hc], Wlin[(2 * a + 1) * HH + hc]}
                        : splat2(0.0f);
    const v2f blv = (v2f){blin[2 * a], blin[2 * a + 1]};

    // act0: sigmoid (a=0: i) or tanh = 2*sig-1 (a=1: g) — scale pre-folded.
    const float outS = a ? 2.0f : 1.0f;
    const float outB = a ? -1.0f : 0.0f;

    float c1 = 0.0f, c2 = 0.0f;
    sh1[h] = 0.0f;
    sh2[h] = 0.0f;

    const v4f* xp = reinterpret_cast<const v4f*>(x) + (size_t)b * T;
    v2f* op = reinterpret_cast<v2f*>(out) + (size_t)b * T * 2 + a;
    const v4f* s1v = reinterpret_cast<const v4f*>(sh1);
    const v4f* s2v = reinterpret_cast<const v4f*>(sh2);

    // ---- phase stagger: de-phase co-resident waves (numeric no-op) ----
    {
        const int phase = b & 3;
#pragma unroll 1
        for (int i = 0; i < phase; ++i)
            __builtin_amdgcn_s_sleep(7);   // ~448 cyc each
    }

    // ---- prologue: L1(0) with h1_{-1} = 0 (no Whh1 terms) ----
    {
        const v4f x0 = xp[0];
        v2f P = bias1;
        P = fma2(wx[0], splat2(x0.x), P);
        P = fma2(wx[1], splat2(x0.y), P);
        P = fma2(wx[2], splat2(x0.z), P);
        P = fma2(wx[3], splat2(x0.w), P);
        float a0v = fmaf(outS, sig2f(P.x), outB);        // i (a=0) / g (a=1)
        float a1v = sig2f(P.y);                          // f (a=0) / o (a=1)
        float iv, gv, fv, ov;
        bcast_halves(a, a0v, iv, gv);
        bcast_halves(a, a1v, fv, ov);
        (void)fv;                                        // c1 starts at 0
        c1 = iv * gv;
        const float h1n = ov * fmaf(2.0f, sig2f(M2 * c1), -1.0f);
        sh1[h] = h1n;                                    // h1(0)
    }
    v4f xc = xp[(T > 1) ? 1 : 0];                        // x(1)

    // Loop invariant at iteration t: sh1 = h1(t), sh2 = h2(t-1),
    // c1 = c1(t), c2 = c2(t-1), xc = x(t+1).
    for (int t = 0; t < T; ++t) {
        const v4f xn = xp[(t + 2 < T) ? (t + 2) : (T - 1)];  // prefetch x(t+2)

        // ===== 6 independent FMA chains =====
        // Ba/Bb : Wih2 @ h1(t) + bias2       (L2 input path)
        // Bc/Bd : Whh2 @ h2(t-1)             (L2 recurrent path)
        // A0/A1 : Whh1 @ h1(t) + Wih1 @ x(t+1) + bias1   (L1 for step t+1)
        v2f Ba = bias2, Bb = splat2(0.0f);
        v2f A0 = bias1, A1 = splat2(0.0f);
        v2f Bc = splat2(0.0f), Bd = splat2(0.0f);

        A0 = fma2(wx[0], splat2(xc.x), A0);
        A0 = fma2(wx[1], splat2(xc.y), A0);
        A0 = fma2(wx[2], splat2(xc.z), A0);
        A0 = fma2(wx[3], splat2(xc.w), A0);

#pragma unroll
        for (int j = 0; j < 7; ++j) {
            const v4f u = s1v[j];            // h1(t), read ONCE, feeds 2 chains
            const v4f v = s2v[j];            // h2(t-1)
            if (j & 1) {
                Bb = fma2(wi2[4 * j + 0], splat2(u.x), Bb);
                Bb = fma2(wi2[4 * j + 1], splat2(u.y), Bb);
                Bb = fma2(wi2[4 * j + 2], splat2(u.z), Bb);
                Bb = fma2(wi2[4 * j + 3], splat2(u.w), Bb);
                A1 = fma2(wh1[4 * j + 0], splat2(u.x), A1);
                A1 = fma2(wh1[4 * j + 1], splat2(u.y), A1);
                A1 = fma2(wh1[4 * j + 2], splat2(u.z), A1);
                A1 = fma2(wh1[4 * j + 3], splat2(u.w), A1);
                Bd = fma2(wh2[4 * j + 0], splat2(v.x), Bd);
                Bd = fma2(wh2[4 * j + 1], splat2(v.y), Bd);
                Bd = fma2(wh2[4 * j + 2], splat2(v.z), Bd);
                Bd = fma2(wh2[4 * j + 3], splat2(v.w), Bd);
            } else {
                Ba = fma2(wi2[4 * j + 0], splat2(u.x), Ba);
                Ba = fma2(wi2[4 * j + 1], splat2(u.y), Ba);
                Ba = fma2(wi2[4 * j + 2], splat2(u.z), Ba);
                Ba = fma2(wi2[4 * j + 3], splat2(u.w), Ba);
                A0 = fma2(wh1[4 * j + 0], splat2(u.x), A0);
                A0 = fma2(wh1[4 * j + 1], splat2(u.y), A0);
                A0 = fma2(wh1[4 * j + 2], splat2(u.z), A0);
                A0 = fma2(wh1[4 * j + 3], splat2(u.w), A0);
                Bc = fma2(wh2[4 * j + 0], splat2(v.x), Bc);
                Bc = fma2(wh2[4 * j + 1], splat2(v.y), Bc);
                Bc = fma2(wh2[4 * j + 2], splat2(v.z), Bc);
                Bc = fma2(wh2[4 * j + 3], splat2(v.w), Bc);
            }
        }
        {
            const v4f u = s1v[7];            // only elements 28,29 are live
            const v4f v = s2v[7];
            Bb = fma2(wi2[28], splat2(u.x), Bb);
            Bb = fma2(wi2[29], splat2(u.y), Bb);
            A1 = fma2(wh1[28], splat2(u.x), A1);
            A1 = fma2(wh1[29], splat2(u.y), A1);
            Bd = fma2(wh2[28], splat2(v.x), Bd);
            Bd = fma2(wh2[29], splat2(v.y), Bd);
        }

        // ===== two independent activation/update tails, interleaved =====
        const v2f Bv = (Ba + Bb) + (Bc + Bd);
        const v2f Av = A0 + A1;

        float b0 = fmaf(outS, sig2f(Bv.x), outB);        // L2: i/g
        float b1 = sig2f(Bv.y);                          // L2: f/o
        float a0v = fmaf(outS, sig2f(Av.x), outB);       // L1(t+1): i/g
        float a1v = sig2f(Av.y);                         // L1(t+1): f/o

        float iv2, gv2, fv2, ov2, iv1, gv1, fv1, ov1;
        bcast_halves(a, b0, iv2, gv2);
        bcast_halves(a, b1, fv2, ov2);
        bcast_halves(a, a0v, iv1, gv1);
        bcast_halves(a, a1v, fv1, ov1);

        c2 = fmaf(fv2, c2, iv2 * gv2);
        c1 = fmaf(fv1, c1, iv1 * gv1);
        const float h2n = ov2 * fmaf(2.0f, sig2f(M2 * c2), -1.0f);  // h2(t)
        const float h1n = ov1 * fmaf(2.0f, sig2f(M2 * c1), -1.0f);  // h1(t+1)
        sh2[h] = h2n;
        sh1[h] = h1n;

        // ===== head: out(t) = Wlin @ h2(t) + b — VALU-pipe DPP reduce =====
        const v2f pv = wlo * splat2(h2n);                // 0 on pad lanes
        const float rx = half_reduce(pv.x);
        const float ry = half_reduce(pv.y);
        if ((tid & 31) == 31) {                          // lane31 (a=0), lane63 (a=1)
            op[2 * t] = (v2f){rx + blv.x, ry + blv.y};
        }
        xc = xn;
    }
}

extern "C" void kernel_launch(void* const* d_in, const int* in_sizes, int n_in,
                              void* d_out, int out_size, void* d_ws, size_t ws_size,
                              hipStream_t stream)
{
    const float* x    = (const float*)d_in[0];
    const float* Wih1 = (const float*)d_in[1];
    const float* bih1 = (const float*)d_in[2];
    const float* Whh1 = (const float*)d_in[3];
    const float* bhh1 = (const float*)d_in[4];
    const float* Wih2 = (const float*)d_in[5];
    const float* bih2 = (const float*)d_in[6];
    const float* Whh2 = (const float*)d_in[7];
    const float* bhh2 = (const float*)d_in[8];
    const float* Wlin = (const float*)d_in[9];
    const float* blin = (const float*)d_in[10];
    float* out = (float*)d_out;

    const int T = 1024;
    const int B = in_sizes[0] / (T * DIN);   // 2048

    hipLaunchKernelGGL(lstm2_kernel, dim3(B), dim3(64), 0, stream,
                       x, Wih1, bih1, Whh1, bhh1, Wih2, bih2, Whh2, bhh2,
                       Wlin, blin, out, T);
}